// Round 6
// baseline (155.648 us; speedup 1.0000x reference)
//
#include <hip/hip_runtime.h>

#define TT 1024
#define CC 128
#define LL 128
#define EPSF 1e-7f
#define LN2F 0.69314718055994531f

#define LOG2F(x) __builtin_amdgcn_logf(x)

typedef unsigned int uint;

template <int CTRL>
__device__ __forceinline__ int dpp_i(int old_, int x) {
  return __builtin_amdgcn_update_dpp(old_, x, CTRL, 0xf, 0xf, false);
}
// shift a3 to next lane (wave_shr:1); lane 0 receives 0.0f via bound_ctrl
__device__ __forceinline__ float dpp_shr1_f32(float x) {
  return __uint_as_float((uint)__builtin_amdgcn_update_dpp(
      0, (int)__float_as_uint(x), 0x138, 0xf, 0xf, true));
}

// fp32 -> bf16 bits, round-to-nearest-even (inputs finite positive)
__device__ __forceinline__ uint bf16bits(float x) {
  uint u = __float_as_uint(x);
  return (u + 0x7fffu + ((u >> 16) & 1u)) >> 16;
}

__device__ __forceinline__ float bperm(int byteaddr, float v) {
  return __uint_as_float(
      (uint)__builtin_amdgcn_ds_bpermute(byteaddr, (int)__float_as_uint(v)));
}

// ---- fused CTC: producer waves feed the serial scan through LDS ----
// r0-r5 post-mortems: the 1-wave scan converges to ~96 cy/step under every
// memory organization (fp64->fp32, reg ring, LDS ring, asm ds pipeline,
// wave-specialized producer) -> the scan pace is a compute-cadence floor,
// not a memory stall. But total = scan + ~111us FIXED in every round; the
// fixed part contains prep_kernel (~20-35us) + a second launch. So: FUSE.
// One kernel, 128 blocks x 320 threads. Wave 0 = the r5 consumer,
// UNCHANGED (proven 40.8us pace). Waves 1..4 = producers: normalize
// y_pred rows, gather label probs via ds_bpermute, pack bf16, write the
// same 4-buffer LDS ring + EB array. Ring discipline identical to r5:
// during interval kk producers stage buffer kk+2 into slot (kk+2)&3
// (distance 2 from any consumer read slot); barrier per interval
// publishes. Producer work/interval (8 rows/wave ~1500cy) is well under
// the consumer's ~3060cy -> prep fully hides under the scan. Producer
// math is op-identical to the old prep (fma(v,r,er), same bf16 rounding)
// -> bit-identical result. Eliminates: prep dispatch, 33.5MB ET write +
// 17MB ET read, one launch.

// one lattice step using word wv (bf16 pair) and blank prob pbf
#define CTC_STEP(wv, pbf)                                   \
  do {                                                      \
    const float p1 = __uint_as_float((wv) << 16);           \
    const float p2 = __uint_as_float((wv) & 0xffff0000u);   \
    const float pb = (pbf);                                 \
    const float p3 = dpp_shr1_f32(a3);                      \
    const float n0 = (a0 + p3) * pb;                        \
    const float n1 = __builtin_fmaf(s1f, p3, a0 + a1) * p1; \
    const float n2 = (a2 + a1) * pb;                        \
    const float n3 = __builtin_fmaf(s3f, a1, a3 + a2) * p2; \
    const float n4 = (a4 + a3) * pb;                        \
    a0 = n0; a1 = n1; a2 = n2; a3 = n3; a4 = n4;            \
  } while (0)

#define CTC_QUAD(et, eb)      \
  do {                        \
    CTC_STEP((et).x, (eb).x); \
    CTC_STEP((et).y, (eb).y); \
    CTC_STEP((et).z, (eb).z); \
    CTC_STEP((et).w, (eb).w); \
  } while (0)

// rescale wave-max exponent back to 2^100 (biased 227); e clamped so the
// correction factor stays a normal fp32 even after a catastrophic window
#define CTC_RESCALE()                                                \
  do {                                                               \
    const float m = fmaxf(fmaxf(fmaxf(a0, a1), fmaxf(a2, a3)), a4);  \
    int ke = (int)(__float_as_uint(m) >> 23);                        \
    ke = max(ke, dpp_i<0x111>(ke, ke));                              \
    ke = max(ke, dpp_i<0x112>(ke, ke));                              \
    ke = max(ke, dpp_i<0x114>(ke, ke));                              \
    ke = max(ke, dpp_i<0x118>(ke, ke));                              \
    ke = max(ke, dpp_i<0x142>(ke, ke));                              \
    ke = max(ke, dpp_i<0x143>(ke, ke));                              \
    ke = __builtin_amdgcn_readlane(ke, 63);                          \
    int e = ke - 227; /* biased_exp(max) - (127 + 100) */            \
    e = e < -127 ? -127 : e;                                         \
    const float sc = __uint_as_float((uint)(127 - e) << 23);         \
    a0 *= sc; a1 *= sc; a2 *= sc; a3 *= sc; a4 *= sc;                \
    ell += e;                                                        \
  } while (0)

// producer: stage 8 rows t0..t0+7 (t0 8-aligned). Loads hoisted first
// (8 VMEM in flight), then per-row: wave sum-reduce, normalize, bpermute
// gather of p[lab.x], p[lab.y], bf16 pack; 4 rows batch into one
// conflict-free-ish ds_write_b128. Lane 63 writes the 4 blank probs.
#define STAGE8(t0)                                                          \
  do {                                                                      \
    float2 vv[8];                                                           \
    _Pragma("unroll") for (int j = 0; j < 8; ++j)                           \
        vv[j] = *(const float2*)(Pb + (size_t)((t0) + j) * CC);             \
    _Pragma("unroll") for (int q = 0; q < 2; ++q) {                         \
      uint wds[4];                                                          \
      float nys[4];                                                         \
      _Pragma("unroll") for (int c = 0; c < 4; ++c) {                       \
        const int j = q * 4 + c;                                            \
        float x = (vv[j].x + EPSF) + (vv[j].y + EPSF);                      \
        _Pragma("unroll") for (int off = 32; off > 0; off >>= 1)            \
            x += __shfl_xor(x, off);                                        \
        const float r = 1.0f / x;                                           \
        const float er = EPSF * r;                                          \
        const float nx = __builtin_fmaf(vv[j].x, r, er);                    \
        const float ny = __builtin_fmaf(vv[j].y, r, er);                    \
        const float c1a = bperm(gxb, nx), c1b = bperm(gxb, ny);             \
        const float c2a = bperm(gyb, nx), c2b = bperm(gyb, ny);             \
        const float g1 = sx ? c1b : c1a;                                    \
        const float g2 = sy ? c2b : c2a;                                    \
        wds[c] = (bf16bits(g2) << 16) | bf16bits(g1);                       \
        nys[c] = ny;                                                        \
      }                                                                     \
      const int tq = (t0) + q * 4;                                          \
      uint4 val;                                                            \
      val.x = wds[0]; val.y = wds[1]; val.z = wds[2]; val.w = wds[3];       \
      *(uint4*)((char*)ETl + ((tq >> 5) & 3) * 8192 +                       \
                ((tq >> 2) & 7) * 1024 + L * 16) = val;                     \
      if (L == 63) {                                                        \
        float4 e4;                                                          \
        e4.x = nys[0]; e4.y = nys[1]; e4.z = nys[2]; e4.w = nys[3];         \
        *(float4*)&EBl[tq] = e4;                                            \
      }                                                                     \
    }                                                                       \
  } while (0)

__global__ __launch_bounds__(320) void ctc_fused(const int* __restrict__ yt,
                                                 const float* __restrict__ yp,
                                                 float* __restrict__ out) {
  const int b = blockIdx.x;
  const int tid = threadIdx.x;
  const int L = tid & 63;
  const int w = tid >> 6;  // 0 = scan consumer, 1..4 = producers

  __shared__ uint4 ETl[4][8][64];            // 32 KB ring: 4 bufs x 8 groups
  __shared__ __align__(16) float EBl[TT];    // 4 KB: all blank probs

  const int2 lab = *(const int2*)(yt + b * LL + 2 * L);

  // consumer constants (garbage-but-unused on producer waves)
  const int labm1 = __shfl_up(lab.y, 1);
  const float s1f = ((L > 0) && (lab.x != labm1)) ? 1.0f : 0.0f;  // s=4L+1
  const float s3f = (lab.y != lab.x) ? 1.0f : 0.0f;               // s=4L+3

  // producer constants
  const float* Pb = yp + (size_t)b * TT * CC + 2 * L;
  const int gxb = (lab.x >> 1) << 2, gyb = (lab.y >> 1) << 2;  // byte lanes
  const int sx = lab.x & 1, sy = lab.y & 1;

  // prologue: producers stage buffers 0 and 1 (rows 0..63)
  if (w != 0) {
    STAGE8((w - 1) * 8);
    STAGE8(32 + (w - 1) * 8);
  }
  __syncthreads();  // buffers 0,1 published

  uint4 etA = {0, 0, 0, 0}, etB = {0, 0, 0, 0};
  float4 ebA = {0, 0, 0, 0}, ebB = {0, 0, 0, 0};
  if (w == 0) {
    etA = ((const uint4*)ETl)[L];
    ebA = *(const float4*)&EBl[0];
  }

  // virtual alpha_{-1}: state 0 = 2^100, rest 0; first step yields alpha_0
  float a0 = (w == 0 && L == 0) ? 0x1.0p100f : 0.0f;
  float a1 = 0.0f, a2 = 0.0f, a3 = 0.0f, a4 = 0.0f;
  int ell = -100;  // wave-uniform: alpha_true = a * 2^ell

  // 32 intervals x 32 steps (8 groups); rescale every 4 groups
#pragma unroll 1
  for (int kk = 0; kk < 32; ++kk) {
    if (w == 0) {
      // consume buffer kk (8 groups), 1-group-ahead A/B rotation (= r5)
      const uint4* cur = (const uint4*)ETl + (size_t)(kk & 3) * 512;
      const float4* ebp = (const float4*)&EBl[kk * 32];
      etB = cur[1 * 64 + L]; ebB = ebp[1];
      CTC_QUAD(etA, ebA);  // g0
      etA = cur[2 * 64 + L]; ebA = ebp[2];
      CTC_QUAD(etB, ebB);  // g1
      etB = cur[3 * 64 + L]; ebB = ebp[3];
      CTC_QUAD(etA, ebA);  // g2
      etA = cur[4 * 64 + L]; ebA = ebp[4];
      CTC_QUAD(etB, ebB);  // g3
      CTC_RESCALE();
      etB = cur[5 * 64 + L]; ebB = ebp[5];
      CTC_QUAD(etA, ebA);  // g4
      etA = cur[6 * 64 + L]; ebA = ebp[6];
      CTC_QUAD(etB, ebB);  // g5
      etB = cur[7 * 64 + L]; ebB = ebp[7];
      CTC_QUAD(etA, ebA);  // g6
      // pre-read next buffer's group 0 (staged interval kk-1, published)
      etA = ((const uint4*)ETl)[(size_t)((kk + 1) & 3) * 512 + L];
      ebA = *(const float4*)&EBl[(kk < 31) ? (kk + 1) * 32 : 1020];
      CTC_QUAD(etB, ebB);  // g7
      CTC_RESCALE();
    } else if (kk < 30) {
      // stage buffer kk+2 into slot (kk+2)&3 — distance 2 from reads
      STAGE8((kk + 2) * 32 + (w - 1) * 8);
    }
    __syncthreads();
  }

  if (tid == 63) {  // consumer wave, lane 63
    // states 255 (=a3), 256 (=a4): loglik = ln2 * (ell + log2(a3+a4))
    float s = a3 + a4;
    if (s < 1e-37f) s = 1e-37f;  // stay normal; loud-but-finite floor
    out[b] = -LN2F * ((float)ell + LOG2F(s));
  }
}

extern "C" void kernel_launch(void* const* d_in, const int* in_sizes, int n_in,
                              void* d_out, int out_size, void* d_ws,
                              size_t ws_size, hipStream_t stream) {
  (void)d_ws; (void)ws_size; (void)n_in; (void)out_size;
  const int* yt = (const int*)d_in[0];
  const float* yp = (const float*)d_in[1];
  float* out = (float*)d_out;
  const int B = in_sizes[0] / LL;  // 128
  hipLaunchKernelGGL(ctc_fused, dim3(B), dim3(320), 0, stream, yt, yp, out);
}

// Round 7
// 144.078 us; speedup vs baseline: 1.0803x; 1.0803x over previous
//
#include <hip/hip_runtime.h>

#define TT 1024
#define CC 128
#define LL 128
#define EPSF 1e-7f
#define LN2F 0.69314718055994531f

#define LOG2F(x) __builtin_amdgcn_logf(x)

typedef unsigned int uint;

template <int CTRL>
__device__ __forceinline__ int dpp_i(int old_, int x) {
  return __builtin_amdgcn_update_dpp(old_, x, CTRL, 0xf, 0xf, false);
}
// DPP with bound_ctrl: invalid lanes read 0 (for additive reductions)
template <int CTRL>
__device__ __forceinline__ float dpp0f(float x) {
  return __uint_as_float((uint)__builtin_amdgcn_update_dpp(
      0, (int)__float_as_uint(x), CTRL, 0xf, 0xf, true));
}
// shift a3 to next lane (wave_shr:1); lane 0 receives 0.0f via bound_ctrl
__device__ __forceinline__ float dpp_shr1_f32(float x) {
  return __uint_as_float((uint)__builtin_amdgcn_update_dpp(
      0, (int)__float_as_uint(x), 0x138, 0xf, 0xf, true));
}
__device__ __forceinline__ float readlane63_f(float v) {
  return __uint_as_float(
      (uint)__builtin_amdgcn_readlane((int)__float_as_uint(v), 63));
}

// fp32 -> bf16 bits, round-to-nearest-even (inputs finite positive)
__device__ __forceinline__ uint bf16bits(float x) {
  uint u = __float_as_uint(x);
  return (u + 0x7fffu + ((u >> 16) & 1u)) >> 16;
}

__device__ __forceinline__ float bperm(int byteaddr, float v) {
  return __uint_as_float(
      (uint)__builtin_amdgcn_ds_bpermute(byteaddr, (int)__float_as_uint(v)));
}

// ---- fused CTC: producer waves feed the serial scan through LDS ----
// One kernel, 128 blocks x 320 threads. Wave 0 = the r5 consumer, UNCHANGED
// (proven 40.8us pace). Waves 1..4 = producers staging the same 4-buffer
// LDS ring + EB array (interval kk stages buffer kk+2 -> slot (kk+2)&3,
// ring distance 2 from consumer reads; barrier per interval publishes).
//
// r6 post-mortem: producers were the critical path — the row-sum used 6
// DEPENDENT __shfl_xor per row (ds_swizzle = LDS pipe), serial over 8 rows
// (~48 LDS round-trips ~ 2900cy/STAGE8) and ~370 LDS ops/interval from 4
// waves contended the CU's single LDS pipe against the consumer's ds_reads
// (SQ_LDS_BANK_CONFLICT 0 -> 1.05M, interval 3060 -> 6300cy). Fix: row
// sums via the canonical DPP reduction (row_shr 1,2,4,8 + row_bcast15 +
// row_bcast31 + readlane 63 — same ctrl sequence CTC_RESCALE already
// uses, proven), adds with bound_ctrl 0-fill, all 8 rows level-interleaved
// so the chains pipeline in the VALU. Zero LDS ops in the reduction;
// producer LDS traffic/interval drops ~84 -> ~36 ops/wave (bpermute
// label-gathers + 2 ds_writes).

// one lattice step using word wv (bf16 pair) and blank prob pbf
#define CTC_STEP(wv, pbf)                                   \
  do {                                                      \
    const float p1 = __uint_as_float((wv) << 16);           \
    const float p2 = __uint_as_float((wv) & 0xffff0000u);   \
    const float pb = (pbf);                                 \
    const float p3 = dpp_shr1_f32(a3);                      \
    const float n0 = (a0 + p3) * pb;                        \
    const float n1 = __builtin_fmaf(s1f, p3, a0 + a1) * p1; \
    const float n2 = (a2 + a1) * pb;                        \
    const float n3 = __builtin_fmaf(s3f, a1, a3 + a2) * p2; \
    const float n4 = (a4 + a3) * pb;                        \
    a0 = n0; a1 = n1; a2 = n2; a3 = n3; a4 = n4;            \
  } while (0)

#define CTC_QUAD(et, eb)      \
  do {                        \
    CTC_STEP((et).x, (eb).x); \
    CTC_STEP((et).y, (eb).y); \
    CTC_STEP((et).z, (eb).z); \
    CTC_STEP((et).w, (eb).w); \
  } while (0)

// rescale wave-max exponent back to 2^100 (biased 227); e clamped so the
// correction factor stays a normal fp32 even after a catastrophic window
#define CTC_RESCALE()                                                \
  do {                                                               \
    const float m = fmaxf(fmaxf(fmaxf(a0, a1), fmaxf(a2, a3)), a4);  \
    int ke = (int)(__float_as_uint(m) >> 23);                        \
    ke = max(ke, dpp_i<0x111>(ke, ke));                              \
    ke = max(ke, dpp_i<0x112>(ke, ke));                              \
    ke = max(ke, dpp_i<0x114>(ke, ke));                              \
    ke = max(ke, dpp_i<0x118>(ke, ke));                              \
    ke = max(ke, dpp_i<0x142>(ke, ke));                              \
    ke = max(ke, dpp_i<0x143>(ke, ke));                              \
    ke = __builtin_amdgcn_readlane(ke, 63);                          \
    int e = ke - 227; /* biased_exp(max) - (127 + 100) */            \
    e = e < -127 ? -127 : e;                                         \
    const float sc = __uint_as_float((uint)(127 - e) << 23);         \
    a0 *= sc; a1 *= sc; a2 *= sc; a3 *= sc; a4 *= sc;                \
    ell += e;                                                        \
  } while (0)

// producer: stage 8 rows t0..t0+7 (t0 8-aligned). Loads issued together
// first; row sums via level-interleaved DPP reduction (VALU only, result
// in lane 63 of each chain); per row: normalize, bpermute-gather the two
// label probs, bf16 pack; 4 rows batch into one ds_write_b128. Lane 63
// writes the 4 blank probs.
#define STAGE8(t0)                                                          \
  do {                                                                      \
    float2 vv[8];                                                           \
    _Pragma("unroll") for (int j = 0; j < 8; ++j)                           \
        vv[j] = *(const float2*)(Pb + (size_t)((t0) + j) * CC);             \
    float ss[8];                                                            \
    _Pragma("unroll") for (int j = 0; j < 8; ++j)                           \
        ss[j] = (vv[j].x + vv[j].y) + (2.0f * EPSF);                        \
    _Pragma("unroll") for (int j = 0; j < 8; ++j)                           \
        ss[j] += dpp0f<0x111>(ss[j]); /* row_shr:1 */                       \
    _Pragma("unroll") for (int j = 0; j < 8; ++j)                           \
        ss[j] += dpp0f<0x112>(ss[j]); /* row_shr:2 */                       \
    _Pragma("unroll") for (int j = 0; j < 8; ++j)                           \
        ss[j] += dpp0f<0x114>(ss[j]); /* row_shr:4 */                       \
    _Pragma("unroll") for (int j = 0; j < 8; ++j)                           \
        ss[j] += dpp0f<0x118>(ss[j]); /* row_shr:8 */                       \
    _Pragma("unroll") for (int j = 0; j < 8; ++j)                           \
        ss[j] += dpp0f<0x142>(ss[j]); /* row_bcast15 */                     \
    _Pragma("unroll") for (int j = 0; j < 8; ++j)                           \
        ss[j] += dpp0f<0x143>(ss[j]); /* row_bcast31: total in lane 63 */   \
    _Pragma("unroll") for (int q = 0; q < 2; ++q) {                         \
      uint wds[4];                                                          \
      float nys[4];                                                         \
      _Pragma("unroll") for (int c = 0; c < 4; ++c) {                       \
        const int j = q * 4 + c;                                            \
        const float x = readlane63_f(ss[j]);                                \
        const float r = 1.0f / x;                                           \
        const float er = EPSF * r;                                          \
        const float nx = __builtin_fmaf(vv[j].x, r, er);                    \
        const float ny = __builtin_fmaf(vv[j].y, r, er);                    \
        const float c1a = bperm(gxb, nx), c1b = bperm(gxb, ny);             \
        const float c2a = bperm(gyb, nx), c2b = bperm(gyb, ny);             \
        const float g1 = sx ? c1b : c1a;                                    \
        const float g2 = sy ? c2b : c2a;                                    \
        wds[c] = (bf16bits(g2) << 16) | bf16bits(g1);                       \
        nys[c] = ny;                                                        \
      }                                                                     \
      const int tq = (t0) + q * 4;                                          \
      uint4 val;                                                            \
      val.x = wds[0]; val.y = wds[1]; val.z = wds[2]; val.w = wds[3];       \
      *(uint4*)((char*)ETl + ((tq >> 5) & 3) * 8192 +                       \
                ((tq >> 2) & 7) * 1024 + L * 16) = val;                     \
      if (L == 63) {                                                        \
        float4 e4;                                                          \
        e4.x = nys[0]; e4.y = nys[1]; e4.z = nys[2]; e4.w = nys[3];         \
        *(float4*)&EBl[tq] = e4;                                            \
      }                                                                     \
    }                                                                       \
  } while (0)

__global__ __launch_bounds__(320) void ctc_fused(const int* __restrict__ yt,
                                                 const float* __restrict__ yp,
                                                 float* __restrict__ out) {
  const int b = blockIdx.x;
  const int tid = threadIdx.x;
  const int L = tid & 63;
  const int w = tid >> 6;  // 0 = scan consumer, 1..4 = producers

  __shared__ uint4 ETl[4][8][64];            // 32 KB ring: 4 bufs x 8 groups
  __shared__ __align__(16) float EBl[TT];    // 4 KB: all blank probs

  const int2 lab = *(const int2*)(yt + b * LL + 2 * L);

  // consumer constants (garbage-but-unused on producer waves)
  const int labm1 = __shfl_up(lab.y, 1);
  const float s1f = ((L > 0) && (lab.x != labm1)) ? 1.0f : 0.0f;  // s=4L+1
  const float s3f = (lab.y != lab.x) ? 1.0f : 0.0f;               // s=4L+3

  // producer constants
  const float* Pb = yp + (size_t)b * TT * CC + 2 * L;
  const int gxb = (lab.x >> 1) << 2, gyb = (lab.y >> 1) << 2;  // byte lanes
  const int sx = lab.x & 1, sy = lab.y & 1;

  // prologue: producers stage buffers 0 and 1 (rows 0..63)
  if (w != 0) {
    STAGE8((w - 1) * 8);
    STAGE8(32 + (w - 1) * 8);
  }
  __syncthreads();  // buffers 0,1 published

  uint4 etA = {0, 0, 0, 0}, etB = {0, 0, 0, 0};
  float4 ebA = {0, 0, 0, 0}, ebB = {0, 0, 0, 0};
  if (w == 0) {
    etA = ((const uint4*)ETl)[L];
    ebA = *(const float4*)&EBl[0];
  }

  // virtual alpha_{-1}: state 0 = 2^100, rest 0; first step yields alpha_0
  float a0 = (w == 0 && L == 0) ? 0x1.0p100f : 0.0f;
  float a1 = 0.0f, a2 = 0.0f, a3 = 0.0f, a4 = 0.0f;
  int ell = -100;  // wave-uniform: alpha_true = a * 2^ell

  // 32 intervals x 32 steps (8 groups); rescale every 4 groups
#pragma unroll 1
  for (int kk = 0; kk < 32; ++kk) {
    if (w == 0) {
      // consume buffer kk (8 groups), 1-group-ahead A/B rotation (= r5)
      const uint4* cur = (const uint4*)ETl + (size_t)(kk & 3) * 512;
      const float4* ebp = (const float4*)&EBl[kk * 32];
      etB = cur[1 * 64 + L]; ebB = ebp[1];
      CTC_QUAD(etA, ebA);  // g0
      etA = cur[2 * 64 + L]; ebA = ebp[2];
      CTC_QUAD(etB, ebB);  // g1
      etB = cur[3 * 64 + L]; ebB = ebp[3];
      CTC_QUAD(etA, ebA);  // g2
      etA = cur[4 * 64 + L]; ebA = ebp[4];
      CTC_QUAD(etB, ebB);  // g3
      CTC_RESCALE();
      etB = cur[5 * 64 + L]; ebB = ebp[5];
      CTC_QUAD(etA, ebA);  // g4
      etA = cur[6 * 64 + L]; ebA = ebp[6];
      CTC_QUAD(etB, ebB);  // g5
      etB = cur[7 * 64 + L]; ebB = ebp[7];
      CTC_QUAD(etA, ebA);  // g6
      // pre-read next buffer's group 0 (staged interval kk-1, published)
      etA = ((const uint4*)ETl)[(size_t)((kk + 1) & 3) * 512 + L];
      ebA = *(const float4*)&EBl[(kk < 31) ? (kk + 1) * 32 : 1020];
      CTC_QUAD(etB, ebB);  // g7
      CTC_RESCALE();
    } else if (kk < 30) {
      // stage buffer kk+2 into slot (kk+2)&3 — distance 2 from reads
      STAGE8((kk + 2) * 32 + (w - 1) * 8);
    }
    __syncthreads();
  }

  if (tid == 63) {  // consumer wave, lane 63
    // states 255 (=a3), 256 (=a4): loglik = ln2 * (ell + log2(a3+a4))
    float s = a3 + a4;
    if (s < 1e-37f) s = 1e-37f;  // stay normal; loud-but-finite floor
    out[b] = -LN2F * ((float)ell + LOG2F(s));
  }
}

extern "C" void kernel_launch(void* const* d_in, const int* in_sizes, int n_in,
                              void* d_out, int out_size, void* d_ws,
                              size_t ws_size, hipStream_t stream) {
  (void)d_ws; (void)ws_size; (void)n_in; (void)out_size;
  const int* yt = (const int*)d_in[0];
  const float* yp = (const float*)d_in[1];
  float* out = (float*)d_out;
  const int B = in_sizes[0] / LL;  // 128
  hipLaunchKernelGGL(ctc_fused, dim3(B), dim3(320), 0, stream, yt, yp, out);
}